// Round 1
// baseline (86.952 us; speedup 1.0000x reference)
//
#include <hip/hip_runtime.h>

#define NPTS 4096            // forbidden points
#define PTS_PER_BLOCK 128    // trajectory points per block
#define SEGS 8               // N-segments per block (threads 256 = 32 slots x 8 segs)
#define SEG_LEN (NPTS / SEGS) // 512
#define K 4                  // points per thread

__global__ __launch_bounds__(256) void nearest_linf_kernel(
    const float* __restrict__ A,   // [32768, 2]
    const float* __restrict__ B,   // [2, 4096]  (all x, then all y)
    float* __restrict__ out)       // [32768, 2]
{
    __shared__ float2 sB[NPTS];                     // 32 KB interleaved (x,y)
    __shared__ float  pbest[SEGS][PTS_PER_BLOCK];   // 4 KB
    __shared__ int    pidx [SEGS][PTS_PER_BLOCK];   // 4 KB

    const int t = threadIdx.x;

    // Stage B into LDS as interleaved pairs; coalesced global reads.
    for (int i = t; i < NPTS; i += 256) {
        sB[i] = make_float2(B[i], B[NPTS + i]);
    }
    __syncthreads();

    const int P0   = blockIdx.x * PTS_PER_BLOCK;
    const int s    = t >> 5;    // segment 0..7 (2 distinct LDS addrs per wave -> free broadcast)
    const int slot = t & 31;    // point-slot 0..31

    float ax[K], ay[K], best[K];
    int   bidx[K];
    #pragma unroll
    for (int j = 0; j < K; ++j) {
        const int p = P0 + slot * K + j;
        const float2 a = reinterpret_cast<const float2*>(A)[p];
        ax[j]  = a.x;
        ay[j]  = a.y;
        best[j] = 3.402823466e38f;
        bidx[j] = 0;
    }

    // Main scan: one broadcast ds_read_b64 feeds 4 points (24 VALU ops).
    const int n0 = s * SEG_LEN;
    #pragma unroll 4
    for (int k = 0; k < SEG_LEN; ++k) {
        const int n = n0 + k;
        const float2 bp = sB[n];
        #pragma unroll
        for (int j = 0; j < K; ++j) {
            const float d = fmaxf(fabsf(ax[j] - bp.x), fabsf(ay[j] - bp.y));
            const bool lt = d < best[j];          // strict < keeps FIRST min (argmin semantics)
            best[j] = lt ? d : best[j];
            bidx[j] = lt ? n : bidx[j];
        }
    }

    #pragma unroll
    for (int j = 0; j < K; ++j) {
        const int lp = slot * K + j;
        pbest[s][lp] = best[j];
        pidx [s][lp] = bidx[j];
    }
    __syncthreads();

    // Cross-segment reduce: ascending s with strict < keeps the globally-first argmin,
    // since segment s holds indices [s*512, (s+1)*512) in ascending order.
    if (t < PTS_PER_BLOCK) {
        float bv = pbest[0][t];
        int   bi = pidx [0][t];
        #pragma unroll
        for (int ss = 1; ss < SEGS; ++ss) {
            const float v = pbest[ss][t];
            const int   i = pidx [ss][t];
            const bool lt = v < bv;
            bv = lt ? v : bv;
            bi = lt ? i : bi;
        }
        const int p = P0 + t;
        const float2 a  = reinterpret_cast<const float2*>(A)[p];
        const float2 bp = sB[bi];
        // Same fp32 subtract as the reference -> bitwise-identical output.
        reinterpret_cast<float2*>(out)[p] = make_float2(a.x - bp.x, a.y - bp.y);
    }
}

extern "C" void kernel_launch(void* const* d_in, const int* in_sizes, int n_in,
                              void* d_out, int out_size, void* d_ws, size_t ws_size,
                              hipStream_t stream) {
    const float* A = (const float*)d_in[0];   // [64*512, 2] fp32
    const float* B = (const float*)d_in[1];   // [2, 4096]   fp32
    float* out = (float*)d_out;               // [64*512, 2] fp32

    const int total_pts = in_sizes[0] / 2;    // 32768
    const int blocks = (total_pts + PTS_PER_BLOCK - 1) / PTS_PER_BLOCK;  // 256

    hipLaunchKernelGGL(nearest_linf_kernel, dim3(blocks), dim3(256), 0, stream,
                       A, B, out);
}

// Round 2
// 83.984 us; speedup vs baseline: 1.0353x; 1.0353x over previous
//
#include <hip/hip_runtime.h>

#define NPTS 4096
#define PTS_PER_BLOCK 128
#define SEGS 8
#define SEG_LEN (NPTS / SEGS)     // 512 candidates per thread
#define K 4                       // points per thread
#define CHUNK 16
#define NCHUNK (SEG_LEN / CHUNK)  // 32
#define FLT_BIG 3.402823466e38f

__global__ __launch_bounds__(256) void nearest_linf_kernel(
    const float* __restrict__ A,   // [32768, 2]
    const float* __restrict__ B,   // [2, 4096]  (all x, then all y)
    float* __restrict__ out)       // [32768, 2]
{
    __shared__ __align__(16) float2 sB[NPTS];       // 32 KB interleaved (x,y)
    __shared__ float  pbest[SEGS][PTS_PER_BLOCK];   // 4 KB
    __shared__ int    pidx [SEGS][PTS_PER_BLOCK];   // 4 KB

    const int t = threadIdx.x;

    // Stage B into LDS as interleaved pairs; coalesced global reads.
    for (int i = t; i < NPTS; i += 256) {
        sB[i] = make_float2(B[i], B[NPTS + i]);
    }
    __syncthreads();

    const int P0   = blockIdx.x * PTS_PER_BLOCK;
    const int s    = t >> 5;    // segment 0..7 (2 distinct LDS addrs/wave -> free 2-way broadcast)
    const int slot = t & 31;    // point-slot 0..31

    float2 a[K];
    float  best[K];
    int    bbase[K];            // base index of winning chunk
    #pragma unroll
    for (int j = 0; j < K; ++j) {
        a[j]     = reinterpret_cast<const float2*>(A)[P0 + slot * K + j];
        best[j]  = FLT_BIG;
        bbase[j] = s * SEG_LEN;
    }

    const float4* sB4 = reinterpret_cast<const float4*>(sB);
    const int n0 = s * SEG_LEN;

    // Phase 1: chunked min (no per-candidate index tracking).
    // Per ds_read_b128: 2 candidates x 4 points; per cand-point ~2.5 VALU ops
    // (pk-sub + max(abs,abs) + v_min3 merge).
    for (int c = 0; c < NCHUNK; ++c) {
        const int cb = n0 + c * CHUNK;
        float cmin[K];
        #pragma unroll
        for (int j = 0; j < K; ++j) cmin[j] = FLT_BIG;

        #pragma unroll
        for (int r = 0; r < CHUNK / 2; ++r) {
            const float4 q = sB4[(cb >> 1) + r];   // candidates 2r, 2r+1 of chunk
            #pragma unroll
            for (int j = 0; j < K; ++j) {
                const float d0 = fmaxf(fabsf(a[j].x - q.x), fabsf(a[j].y - q.y));
                const float d1 = fmaxf(fabsf(a[j].x - q.z), fabsf(a[j].y - q.w));
                cmin[j] = fminf(cmin[j], fminf(d0, d1));   // -> v_min3_f32
            }
        }
        #pragma unroll
        for (int j = 0; j < K; ++j) {
            const bool lt = cmin[j] < best[j];   // strict <: first chunk achieving min wins
            best[j]  = lt ? cmin[j] : best[j];
            bbase[j] = lt ? cb : bbase[j];
        }
    }

    // Phase 2: rescan the winning chunk for the FIRST candidate with d == best.
    // fp32 sub/abs/max are deterministic -> exact equality reproduces jnp.argmin.
    #pragma unroll
    for (int j = 0; j < K; ++j) {
        int idx = -1;
        for (int n = bbase[j]; n < bbase[j] + CHUNK; ++n) {
            const float2 bp = sB[n];
            const float d = fmaxf(fabsf(a[j].x - bp.x), fabsf(a[j].y - bp.y));
            if (idx < 0 && d == best[j]) idx = n;
        }
        pbest[s][slot * K + j] = best[j];
        pidx [s][slot * K + j] = idx;
    }
    __syncthreads();

    // Cross-segment reduce: ascending s with strict < keeps the globally-first
    // argmin (segment s holds ascending index range [s*512, (s+1)*512)).
    if (t < PTS_PER_BLOCK) {
        float bv = pbest[0][t];
        int   bi = pidx [0][t];
        #pragma unroll
        for (int ss = 1; ss < SEGS; ++ss) {
            const float v = pbest[ss][t];
            const int   i = pidx [ss][t];
            const bool lt = v < bv;
            bv = lt ? v : bv;
            bi = lt ? i : bi;
        }
        const int p = P0 + t;
        const float2 aa = reinterpret_cast<const float2*>(A)[p];
        const float2 bp = sB[bi];
        // Same fp32 subtract as the reference -> bitwise-identical output.
        reinterpret_cast<float2*>(out)[p] = make_float2(aa.x - bp.x, aa.y - bp.y);
    }
}

extern "C" void kernel_launch(void* const* d_in, const int* in_sizes, int n_in,
                              void* d_out, int out_size, void* d_ws, size_t ws_size,
                              hipStream_t stream) {
    const float* A = (const float*)d_in[0];   // [64*512, 2] fp32
    const float* B = (const float*)d_in[1];   // [2, 4096]   fp32
    float* out = (float*)d_out;               // [64*512, 2] fp32

    const int total_pts = in_sizes[0] / 2;    // 32768
    const int blocks = (total_pts + PTS_PER_BLOCK - 1) / PTS_PER_BLOCK;  // 256

    hipLaunchKernelGGL(nearest_linf_kernel, dim3(blocks), dim3(256), 0, stream,
                       A, B, out);
}